// Round 12
// baseline (1269.873 us; speedup 1.0000x reference)
//
#include <hip/hip_runtime.h>

#define DPDIM 32         // path/link state dim
#define GCOLS 96         // 3*DPDIM gate columns
#define PLEN 8
#define T_ITERS 8
#define RUNITS 256

// ---------------- fast activations (v_exp_f32 + v_rcp_f32) ----------------
__device__ __forceinline__ float fast_sigmoid(float a) {
    return __builtin_amdgcn_rcpf(1.0f + __expf(-a));
}
__device__ __forceinline__ float fast_tanh(float a) {
    // tanh(x) = 1 - 2/(1+e^{2x}); stable at both infinities
    return 1.0f - 2.0f * __builtin_amdgcn_rcpf(1.0f + __expf(2.0f * a));
}

#define ACC4F(A, s, V) \
    A.x = fmaf((s), (V).x, A.x); A.y = fmaf((s), (V).y, A.y); \
    A.z = fmaf((s), (V).z, A.z); A.w = fmaf((s), (V).w, A.w);

// ---------------- init states ----------------
__global__ __launch_bounds__(256) void init_kernel(
    const float* __restrict__ traffic, const float* __restrict__ packets,
    const float* __restrict__ eqlam, const float* __restrict__ avgpkt,
    const float* __restrict__ capacity, const float* __restrict__ queues,
    float* __restrict__ path_state, float* __restrict__ link_state,
    int n_paths, int n_links)
{
    int i = blockIdx.x * 256 + threadIdx.x;
    if (i < n_paths) {
        float4* row = (float4*)(path_state + (size_t)i * DPDIM);
        row[0] = make_float4(traffic[i], packets[i], eqlam[i], avgpkt[i]);
        float4 z = make_float4(0.f, 0.f, 0.f, 0.f);
        #pragma unroll
        for (int k = 1; k < 8; ++k) row[k] = z;
    }
    if (i < n_links) {
        float4* row = (float4*)(link_state + (size_t)i * DPDIM);
        row[0] = make_float4(capacity[i], queues[i], 0.f, 0.f);
        float4 z = make_float4(0.f, 0.f, 0.f, 0.f);
        #pragma unroll
        for (int k = 1; k < 8; ++k) row[k] = z;
    }
}

// ---------------- weight transpose: W[k][96] -> T[jb][k][12], 4 at once ----
__global__ __launch_bounds__(256) void transpose_w4_kernel(
    const float* __restrict__ W0, float* __restrict__ T0,
    const float* __restrict__ W1, float* __restrict__ T1,
    const float* __restrict__ W2, float* __restrict__ T2,
    const float* __restrict__ W3, float* __restrict__ T3)
{
    int i = blockIdx.x * 256 + threadIdx.x;
    if (i >= 4*8*32*12) return;
    int sel = i / (8*32*12);
    int j   = i % (8*32*12);
    int idx = j % 12;
    int k   = (j / 12) % 32;
    int jb  = j / (12*32);
    int gate = idx >> 2, c = idx & 3;
    const float* W = (sel == 0) ? W0 : (sel == 1) ? W1 : (sel == 2) ? W2 : W3;
    float*       T = (sel == 0) ? T0 : (sel == 1) ? T1 : (sel == 2) ? T2 : T3;
    T[j] = W[k*GCOLS + gate*32 + jb*4 + c];
}

// ---------------- CSR build ----------------
__global__ __launch_bounds__(256) void zero_counts_kernel(int* __restrict__ counts, int n) {
    int i = blockIdx.x * 256 + threadIdx.x;
    if (i < n) counts[i] = 0;
}
__global__ __launch_bounds__(256) void hist_kernel(
    const int* __restrict__ link_to_path, int* __restrict__ counts, int n) {
    int i = blockIdx.x * 256 + threadIdx.x;
    if (i < n) atomicAdd(&counts[link_to_path[i]], 1);
}
__global__ __launch_bounds__(1024) void scan_kernel(
    const int* __restrict__ counts, int* __restrict__ offsets,
    int* __restrict__ cursor, int n)
{
    __shared__ int s[1024];
    int t = threadIdx.x;
    int chunk = (n + 1023) >> 10;
    int lo = t * chunk;
    int hi = lo + chunk; if (hi > n) hi = n;
    int local = 0;
    for (int i = lo; i < hi; ++i) local += counts[i];
    s[t] = local;
    __syncthreads();
    for (int d = 1; d < 1024; d <<= 1) {
        int v = (t >= d) ? s[t - d] : 0;
        __syncthreads();
        s[t] += v;
        __syncthreads();
    }
    int base = (t > 0) ? s[t - 1] : 0;
    for (int i = lo; i < hi; ++i) {
        offsets[i] = base; cursor[i] = base; base += counts[i];
    }
    if (t == 1023) offsets[n] = s[1023];
}
__global__ __launch_bounds__(256) void fill_kernel(
    const int* __restrict__ link_to_path, int* __restrict__ cursor,
    int* __restrict__ entries, int n) {
    int e = blockIdx.x * 256 + threadIdx.x;
    if (e < n) {
        int l = link_to_path[e];
        int pos = atomicAdd(&cursor[l], 1);
        entries[pos] = e >> 3;   // path id (PLEN == 8)
    }
}

// ---------------- standalone gate_pre (pre-loop only) ----------------------
__global__ __launch_bounds__(256, 1) void gate_pre_kernel(
    const float* __restrict__ link_state,
    const float* __restrict__ WpT, const float* __restrict__ bip,
    const float* __restrict__ bhp,
    float* __restrict__ Gi, int* __restrict__ nzf, int n_links)
{
    int t = threadIdx.x;
    int pe = t & 63;
    int eps = __builtin_amdgcn_readfirstlane(t >> 6);
    int l = blockIdx.x * 64 + pe;
    bool act = l < n_links;
    int ll = act ? l : (n_links - 1);

    float x[DPDIM];
    bool nz = false;
    {
        const float4* row = (const float4*)(link_state + (size_t)ll * DPDIM);
        #pragma unroll
        for (int k4 = 0; k4 < 8; ++k4) {
            float4 v = row[k4];
            x[4*k4+0]=v.x; x[4*k4+1]=v.y; x[4*k4+2]=v.z; x[4*k4+3]=v.w;
            nz = nz || (v.x != 0.f) || (v.y != 0.f) || (v.z != 0.f) || (v.w != 0.f);
        }
    }
    float* G = Gi + (size_t)ll * GCOLS;
    int jb0 = eps*2;
    #pragma unroll 1
    for (int jj = 0; jj < 2; ++jj) {
        int jb = jb0 + jj;                              // wave-uniform
        float4 az = {0,0,0,0}, ar = {0,0,0,0}, ah = {0,0,0,0};
        const float* w = WpT + jb*(32*12);              // uniform s_load base
        #pragma unroll 4
        for (int k = 0; k < DPDIM; ++k) {
            float xk = x[k];
            const float4 wz = *(const float4*)(w);
            const float4 wr = *(const float4*)(w + 4);
            const float4 wh = *(const float4*)(w + 8);
            ACC4F(az, xk, wz); ACC4F(ar, xk, wr); ACC4F(ah, xk, wh);
            w += 12;
        }
        const float4 bz = *(const float4*)(bip + jb*4);
        const float4 br = *(const float4*)(bip + 32 + jb*4);
        const float4 bh = *(const float4*)(bip + 64 + jb*4);
        const float4 cz = *(const float4*)(bhp + jb*4);
        const float4 cr = *(const float4*)(bhp + 32 + jb*4);
        if (act) {
            *(float4*)(G + jb*4)      = make_float4(az.x+bz.x+cz.x, az.y+bz.y+cz.y,
                                                    az.z+bz.z+cz.z, az.w+bz.w+cz.w);
            *(float4*)(G + 32 + jb*4) = make_float4(ar.x+br.x+cr.x, ar.y+br.y+cr.y,
                                                    ar.z+br.z+cr.z, ar.w+br.w+cr.w);
            *(float4*)(G + 64 + jb*4) = make_float4(ah.x+bh.x, ah.y+bh.y,
                                                    ah.z+bh.z, ah.w+bh.w);
        }
    }
    if (act && eps == 0) nzf[l] = nz ? 1 : 0;
}

// ---------------- path GRU: 4 waves, Gi prefetch, own-h in registers -------
// Round-9/11 version (best measured ~96us). FROZEN.
__global__ __launch_bounds__(256, 1) void path_kernel(
    const float* __restrict__ Gi, const int* __restrict__ nzf,
    float* __restrict__ path_state, const int* __restrict__ link_to_path,
    const float* __restrict__ UpT, const float* __restrict__ bhp, int n_paths)
{
    __shared__ float hbuf[2*DPDIM*64];    // 16 KB, [buf][col][pathlane]
    int t = threadIdx.x;
    int pe = t & 63;
    int eps = __builtin_amdgcn_readfirstlane(t >> 6);
    int p = blockIdx.x * 64 + pe;
    bool act = p < n_paths;
    int pp = act ? p : (n_paths - 1);

    float4 hownA, hownB;                  // own 8 columns, live in registers
    {
        const float4* row = (const float4*)(path_state + (size_t)pp * DPDIM + eps*8);
        hownA = row[0]; hownB = row[1];
        int c0 = eps*8;
        hbuf[(c0+0)*64 + pe] = hownA.x; hbuf[(c0+1)*64 + pe] = hownA.y;
        hbuf[(c0+2)*64 + pe] = hownA.z; hbuf[(c0+3)*64 + pe] = hownA.w;
        hbuf[(c0+4)*64 + pe] = hownB.x; hbuf[(c0+5)*64 + pe] = hownB.y;
        hbuf[(c0+6)*64 + pe] = hownB.z; hbuf[(c0+7)*64 + pe] = hownB.w;
    }

    const int jbA = eps*2, jbB = eps*2 + 1;
    const float4 ahA0 = *(const float4*)(bhp + 64 + jbA*4);   // uniform, hoisted
    const float4 ahB0 = *(const float4*)(bhp + 64 + jbB*4);
    const float* wA0 = UpT + jbA*(32*12);                     // uniform bases
    const float* wB0 = UpT + jbB*(32*12);

    // prefetch pipeline: l_s current link, l_n next link
    int l_s = link_to_path[pp*PLEN + 0];
    int l_n = link_to_path[pp*PLEN + 1];
    const float* G0 = Gi + (size_t)l_s * GCOLS;
    float4 pazA = *(const float4*)(G0 + jbA*4);
    float4 parA = *(const float4*)(G0 + 32 + jbA*4);
    float4 pgihA= *(const float4*)(G0 + 64 + jbA*4);
    float4 pazB = *(const float4*)(G0 + jbB*4);
    float4 parB = *(const float4*)(G0 + 32 + jbB*4);
    float4 pgihB= *(const float4*)(G0 + 64 + jbB*4);
    int pnz = nzf[l_s];

    __syncthreads();

    int cur = 0;
    #pragma unroll 1
    for (int s = 0; s < PLEN; ++s) {
        float4 azA = pazA, arA = parA, gihA = pgihA;
        float4 azB = pazB, arB = parB, gihB = pgihB;
        bool nz = act && (pnz != 0);
        if (s < PLEN-1) {                       // issue next-step gathers NOW
            const float* G1 = Gi + (size_t)l_n * GCOLS;
            pazA = *(const float4*)(G1 + jbA*4);
            parA = *(const float4*)(G1 + 32 + jbA*4);
            pgihA= *(const float4*)(G1 + 64 + jbA*4);
            pazB = *(const float4*)(G1 + jbB*4);
            parB = *(const float4*)(G1 + 32 + jbB*4);
            pgihB= *(const float4*)(G1 + 64 + jbB*4);
            pnz = nzf[l_n];
            if (s < PLEN-2) l_n = link_to_path[pp*PLEN + s + 2];
        }
        const float* hold = hbuf + cur*(DPDIM*64) + pe;
        float* hnew = hbuf + (cur^1)*(DPDIM*64) + pe;
#define PWC1(C, j, az, ar, gih, ah, jb, HOWN) { \
        float zz = fast_sigmoid((az).C); \
        float rr = fast_sigmoid((ar).C); \
        float cc = fast_tanh((gih).C + rr * (ah).C); \
        float ho = (HOWN).C; \
        float nx = nz ? (cc + zz * (ho - cc)) : ho; \
        hnew[((jb)*4+(j))*64] = nx; \
        (HOWN).C = nx; }
        {   // jb A
            float4 ah = ahA0;
            const float* w = wA0;
            #pragma unroll 4
            for (int k = 0; k < DPDIM; ++k) {
                float hk = hold[k*64];
                const float4 wz = *(const float4*)(w);
                const float4 wr = *(const float4*)(w + 4);
                const float4 wh = *(const float4*)(w + 8);
                ACC4F(azA, hk, wz); ACC4F(arA, hk, wr); ACC4F(ah, hk, wh);
                w += 12;
            }
            PWC1(x, 0, azA, arA, gihA, ah, jbA, hownA)
            PWC1(y, 1, azA, arA, gihA, ah, jbA, hownA)
            PWC1(z, 2, azA, arA, gihA, ah, jbA, hownA)
            PWC1(w, 3, azA, arA, gihA, ah, jbA, hownA)
        }
        {   // jb B
            float4 ah = ahB0;
            const float* w = wB0;
            #pragma unroll 4
            for (int k = 0; k < DPDIM; ++k) {
                float hk = hold[k*64];
                const float4 wz = *(const float4*)(w);
                const float4 wr = *(const float4*)(w + 4);
                const float4 wh = *(const float4*)(w + 8);
                ACC4F(azB, hk, wz); ACC4F(arB, hk, wr); ACC4F(ah, hk, wh);
                w += 12;
            }
            PWC1(x, 0, azB, arB, gihB, ah, jbB, hownB)
            PWC1(y, 1, azB, arB, gihB, ah, jbB, hownB)
            PWC1(z, 2, azB, arB, gihB, ah, jbB, hownB)
            PWC1(w, 3, azB, arB, gihB, ah, jbB, hownB)
        }
#undef PWC1
        __syncthreads();     // hnew complete + hold reads done across waves
        cur ^= 1;
    }

    if (act) {   // own columns already in registers
        *(float4*)(path_state + (size_t)p * DPDIM + eps*8)     = hownA;
        *(float4*)(path_state + (size_t)p * DPDIM + eps*8 + 4) = hownB;
    }
}

// ---------------- segment sum: 1 wave per link, 2-way entry split ----------
// (round-11 version, FROZEN)
__global__ __launch_bounds__(256) void seg_sum_kernel(
    const float* __restrict__ path_state, const int* __restrict__ offsets,
    const int* __restrict__ entries, float* __restrict__ path_sum, int n_links)
{
    int t = threadIdx.x;
    int lane = t & 63;
    int wid = t >> 6;               // wave 0..3 -> link
    int d = lane & 31;
    int half = lane >> 5;           // 0 or 1
    int l = blockIdx.x * 4 + wid;
    if (l >= n_links) return;
    int beg = offsets[l], end = offsets[l+1];
    float a0 = 0.f, a1 = 0.f, a2 = 0.f, a3 = 0.f;
    int q = beg + half;
    for (; q + 6 < end; q += 8) {
        int p0 = entries[q],   p1 = entries[q+2];
        int p2 = entries[q+4], p3 = entries[q+6];
        a0 += path_state[(size_t)p0 * DPDIM + d];
        a1 += path_state[(size_t)p1 * DPDIM + d];
        a2 += path_state[(size_t)p2 * DPDIM + d];
        a3 += path_state[(size_t)p3 * DPDIM + d];
    }
    for (; q < end; q += 2)
        a0 += path_state[(size_t)entries[q] * DPDIM + d];
    float s = (a0 + a1) + (a2 + a3);
    s += __shfl_down(s, 32);        // combine the two halves (wave64)
    if (half == 0)
        path_sum[(size_t)l * DPDIM + d] = s;
}

// ---------------- fused link GRU + next-iter gate_pre: k-split, 16 waves ---
// 64 links/block, 1024 threads = 16 waves; wave w = (jb = w&7, kh = w>>3).
// Each wave accumulates its 16-k half; kh=1 writes partials to padded LDS
// (stride 17 floats, scalar ops: banks (17*pe+i)%32, lanes pe/pe+32 2-way =
// free); kh=0 combines total = lowSum + highSum, then the round-11 epilogue.
// Halves the serial matmul chain of the most latency-bloated kernel
// (2504 -> 5008 waves, ~1us of real FLOPs under ~17us walltime).
__global__ __launch_bounds__(1024, 1) void link_gate_kernel(
    const float* __restrict__ path_sum, float* __restrict__ link_state,
    const float* __restrict__ WlT, const float* __restrict__ UlT,
    const float* __restrict__ bil, const float* __restrict__ bhl,
    const float* __restrict__ WpT, const float* __restrict__ bip,
    const float* __restrict__ bhp,
    float* __restrict__ Gi, int* __restrict__ nzf, int n_links, int do_gate)
{
    __shared__ float xbuf[DPDIM*64];     // 8 KB [col][lane]  (path_sum)
    __shared__ float hbuf[DPDIM*64];     // 8 KB [col][lane]  (old h)
    __shared__ float nbuf[DPDIM*64];     // 8 KB [col][lane]  (new h)
    __shared__ float pbuf[8*64*17];      // 34.8 KB partials (padded stride)
    int t = threadIdx.x;
    int pe = t & 63;
    int w_ = t >> 6;                                    // 0..15
    int jb = __builtin_amdgcn_readfirstlane(w_ & 7);
    int kh = __builtin_amdgcn_readfirstlane(w_ >> 3);   // 0 or 1
    int l = blockIdx.x * 64 + pe;
    bool act = l < n_links;
    int ll = act ? l : (n_links - 1);
    int c0 = jb*4;
    int kbeg = kh*16;
    float* pb = pbuf + ((size_t)(jb*64) + pe)*17;

    if (kh == 0) {   // waves 0..7 stage x and h (same as round-11)
        float4 x0 = *(const float4*)(path_sum   + (size_t)ll * DPDIM + c0);
        float4 h0 = *(const float4*)(link_state + (size_t)ll * DPDIM + c0);
        xbuf[(c0+0)*64 + pe] = x0.x; xbuf[(c0+1)*64 + pe] = x0.y;
        xbuf[(c0+2)*64 + pe] = x0.z; xbuf[(c0+3)*64 + pe] = x0.w;
        hbuf[(c0+0)*64 + pe] = h0.x; hbuf[(c0+1)*64 + pe] = h0.y;
        hbuf[(c0+2)*64 + pe] = h0.z; hbuf[(c0+3)*64 + pe] = h0.w;
    }
    __syncthreads();

    // ---- phase 1: link GRU, each wave does its 16-k half ----
    {
        float4 az = {0,0,0,0}, ar = {0,0,0,0}, ai = {0,0,0,0}, ah = {0,0,0,0};
        const float* w = WlT + jb*(32*12) + kbeg*12;     // uniform s_load
        const float* u = UlT + jb*(32*12) + kbeg*12;     // uniform s_load
        #pragma unroll 4
        for (int k = 0; k < 16; ++k) {
            float xk = xbuf[(kbeg+k)*64 + pe];
            float hk = hbuf[(kbeg+k)*64 + pe];
            const float4 wz = *(const float4*)(w);
            const float4 wr = *(const float4*)(w + 4);
            const float4 wh = *(const float4*)(w + 8);
            const float4 uz = *(const float4*)(u);
            const float4 ur = *(const float4*)(u + 4);
            const float4 uh = *(const float4*)(u + 8);
            ACC4F(az, xk, wz); ACC4F(az, hk, uz);
            ACC4F(ar, xk, wr); ACC4F(ar, hk, ur);
            ACC4F(ai, xk, wh);
            ACC4F(ah, hk, uh);
            w += 12; u += 12;
        }
        if (kh == 1) {
            pb[0]=az.x;  pb[1]=az.y;  pb[2]=az.z;  pb[3]=az.w;
            pb[4]=ar.x;  pb[5]=ar.y;  pb[6]=ar.z;  pb[7]=ar.w;
            pb[8]=ai.x;  pb[9]=ai.y;  pb[10]=ai.z; pb[11]=ai.w;
            pb[12]=ah.x; pb[13]=ah.y; pb[14]=ah.z; pb[15]=ah.w;
        }
        __syncthreads();
        if (kh == 0) {
            az.x += pb[0];  az.y += pb[1];  az.z += pb[2];  az.w += pb[3];
            ar.x += pb[4];  ar.y += pb[5];  ar.z += pb[6];  ar.w += pb[7];
            ai.x += pb[8];  ai.y += pb[9];  ai.z += pb[10]; ai.w += pb[11];
            ah.x += pb[12]; ah.y += pb[13]; ah.z += pb[14]; ah.w += pb[15];
            const float4 BZI = *(const float4*)(bil + jb*4);
            const float4 BRI = *(const float4*)(bil + 32 + jb*4);
            const float4 BHI = *(const float4*)(bil + 64 + jb*4);
            const float4 BZH = *(const float4*)(bhl + jb*4);
            const float4 BRH = *(const float4*)(bhl + 32 + jb*4);
            const float4 BHH = *(const float4*)(bhl + 64 + jb*4);
            float4 hv;
#define LWC(C, j, DST) { \
            float z = fast_sigmoid(az.C + BZI.C + BZH.C); \
            float r = fast_sigmoid(ar.C + BRI.C + BRH.C); \
            float c = fast_tanh(ai.C + BHI.C + r * (ah.C + BHH.C)); \
            float ho = hbuf[(jb*4+j)*64 + pe]; \
            DST = z*ho + (1.f - z)*c; }
            LWC(x, 0, hv.x) LWC(y, 1, hv.y) LWC(z, 2, hv.z) LWC(w, 3, hv.w)
#undef LWC
            nbuf[(c0+0)*64 + pe] = hv.x; nbuf[(c0+1)*64 + pe] = hv.y;
            nbuf[(c0+2)*64 + pe] = hv.z; nbuf[(c0+3)*64 + pe] = hv.w;
            if (act) *(float4*)(link_state + (size_t)ll * DPDIM + c0) = hv;
        }
    }
    if (!do_gate) return;        // uniform across block
    __syncthreads();

    // ---- phase 2: gate_pre for NEXT iteration, x = new h (nbuf), k-split --
    {
        float4 az = {0,0,0,0}, ar = {0,0,0,0}, ah = {0,0,0,0};
        const float* w = WpT + jb*(32*12) + kbeg*12;     // uniform s_load
        #pragma unroll 4
        for (int k = 0; k < 16; ++k) {
            float xk = nbuf[(kbeg+k)*64 + pe];
            const float4 wz = *(const float4*)(w);
            const float4 wr = *(const float4*)(w + 4);
            const float4 wh = *(const float4*)(w + 8);
            ACC4F(az, xk, wz); ACC4F(ar, xk, wr); ACC4F(ah, xk, wh);
            w += 12;
        }
        if (kh == 1) {
            pb[0]=az.x; pb[1]=az.y; pb[2]=az.z;  pb[3]=az.w;
            pb[4]=ar.x; pb[5]=ar.y; pb[6]=ar.z;  pb[7]=ar.w;
            pb[8]=ah.x; pb[9]=ah.y; pb[10]=ah.z; pb[11]=ah.w;
        }
        __syncthreads();
        if (kh == 0) {
            az.x += pb[0]; az.y += pb[1]; az.z += pb[2];  az.w += pb[3];
            ar.x += pb[4]; ar.y += pb[5]; ar.z += pb[6];  ar.w += pb[7];
            ah.x += pb[8]; ah.y += pb[9]; ah.z += pb[10]; ah.w += pb[11];
            const float4 bz = *(const float4*)(bip + jb*4);
            const float4 br = *(const float4*)(bip + 32 + jb*4);
            const float4 bh = *(const float4*)(bip + 64 + jb*4);
            const float4 cz = *(const float4*)(bhp + jb*4);
            const float4 cr = *(const float4*)(bhp + 32 + jb*4);
            float* G = Gi + (size_t)ll * GCOLS;
            if (act) {
                *(float4*)(G + jb*4)      = make_float4(az.x+bz.x+cz.x, az.y+bz.y+cz.y,
                                                        az.z+bz.z+cz.z, az.w+bz.w+cz.w);
                *(float4*)(G + 32 + jb*4) = make_float4(ar.x+br.x+cr.x, ar.y+br.y+cr.y,
                                                        ar.z+br.z+cr.z, ar.w+br.w+cr.w);
                *(float4*)(G + 64 + jb*4) = make_float4(ah.x+bh.x, ah.y+bh.y,
                                                        ah.z+bh.z, ah.w+bh.w);
            }
            if (jb == 0) {
                bool nz = false;
                #pragma unroll 4
                for (int k = 0; k < DPDIM; ++k)
                    nz = nz || (nbuf[k*64 + pe] != 0.f);
                if (act) nzf[l] = nz ? 1 : 0;
            }
        }
    }
}

// ---------------- readout: lane=link, scalar weights -----------------------
__global__ __launch_bounds__(512, 1) void readout_kernel(
    const float* __restrict__ link_state,
    const float* __restrict__ W1, const float* __restrict__ b1,
    const float* __restrict__ W2, const float* __restrict__ b2,
    const float* __restrict__ W3, const float* __restrict__ b3,
    float* __restrict__ out, int n_links)
{
    __shared__ float s_m[64*257];     // 64.25 KB, r1[link][col] (pad 257)
    __shared__ float s_part[8*64];
    int t = threadIdx.x;
    int u = t & 63;                                     // link lane
    int g = __builtin_amdgcn_readfirstlane(t >> 6);     // wave id 0..7
    int l = blockIdx.x * 64 + u;
    bool act = l < n_links;
    int ll = act ? l : (n_links - 1);

    float x[DPDIM];
    {
        const float4* row = (const float4*)(link_state + (size_t)ll * DPDIM);
        #pragma unroll
        for (int k4 = 0; k4 < 8; ++k4) {
            float4 v = row[k4];
            x[4*k4+0]=v.x; x[4*k4+1]=v.y; x[4*k4+2]=v.z; x[4*k4+3]=v.w;
        }
    }
    // r1 for cols [32g, 32g+32)
    {
        const float* w1p = W1 + 32*g;                   // uniform base
        const float* b1p = b1 + 32*g;
        float acc1[32];
        #pragma unroll
        for (int c = 0; c < 32; ++c) acc1[c] = b1p[c];
        #pragma unroll 2
        for (int k = 0; k < DPDIM; ++k) {
            float xk = x[k];
            #pragma unroll
            for (int c = 0; c < 32; ++c)
                acc1[c] = fmaf(xk, w1p[k*RUNITS + c], acc1[c]);
        }
        #pragma unroll
        for (int c = 0; c < 32; ++c)
            s_m[u*257 + 32*g + c] = fmaxf(acc1[c], 0.f);
    }
    __syncthreads();
    // r2 for cols [32g,32g+32) of link u: 1 LDS read per k -> 32 FMA
    float acc[32];
    {
        const float* w2p = W2 + 32*g;                   // uniform base
        const float* b2p = b2 + 32*g;
        #pragma unroll
        for (int c = 0; c < 32; ++c) acc[c] = b2p[c];
        const float* rrow = s_m + u*257;
        #pragma unroll 2
        for (int k = 0; k < RUNITS; ++k) {
            float rk = rrow[k];
            #pragma unroll
            for (int c = 0; c < 32; ++c)
                acc[c] = fmaf(rk, w2p[k*RUNITS + c], acc[c]);
        }
    }
    // partial dot with w3
    {
        const float* w3p = W3 + 32*g;
        float psum = 0.f;
        #pragma unroll
        for (int c = 0; c < 32; ++c)
            psum += fmaxf(acc[c], 0.f) * w3p[c];
        s_part[g*64 + u] = psum;
    }
    __syncthreads();
    if (t < 64 && act) {
        float ssum = b3[0];
        #pragma unroll
        for (int gg = 0; gg < 8; ++gg) ssum += s_part[gg*64 + u];
        out[l] = ssum;
    }
}

// ---------------- launch ----------------
extern "C" void kernel_launch(void* const* d_in, const int* in_sizes, int n_in,
                              void* d_out, int out_size, void* d_ws, size_t ws_size,
                              hipStream_t stream)
{
    const float* traffic  = (const float*)d_in[0];
    const float* packets  = (const float*)d_in[1];
    const float* eqlam    = (const float*)d_in[2];
    const float* avgpkt   = (const float*)d_in[3];
    const float* capacity = (const float*)d_in[4];
    const float* queues   = (const float*)d_in[5];
    const int* link_to_path = (const int*)d_in[6];
    const float* Wp  = (const float*)d_in[13];
    const float* Up  = (const float*)d_in[14];
    const float* bip = (const float*)d_in[15];
    const float* bhp = (const float*)d_in[16];
    const float* Wl  = (const float*)d_in[17];
    const float* Ul  = (const float*)d_in[18];
    const float* bil = (const float*)d_in[19];
    const float* bhl = (const float*)d_in[20];
    const float* W1  = (const float*)d_in[21];
    const float* b1  = (const float*)d_in[22];
    const float* W2  = (const float*)d_in[23];
    const float* b2  = (const float*)d_in[24];
    const float* W3  = (const float*)d_in[25];
    const float* b3  = (const float*)d_in[26];
    const int n_paths = in_sizes[0];     // 100000
    const int n_links = in_sizes[4];     // 20000
    const int n_ent   = in_sizes[6];     // 800000

    char* ws = (char*)d_ws;
    size_t off = 0;
    auto salloc = [&](size_t bytes) -> void* {
        void* p = ws + off;
        off += (bytes + 255) & ~size_t(255);
        return p;
    };
    float* path_state = (float*)salloc((size_t)n_paths * DPDIM * 4);
    float* link_state = (float*)salloc((size_t)n_links * DPDIM * 4);
    float* Gi         = (float*)salloc((size_t)n_links * GCOLS * 4);
    float* path_sum   = (float*)salloc((size_t)n_links * DPDIM * 4);
    float* UpT   = (float*)salloc((size_t)8 * 32 * 12 * 4);
    float* WpT   = (float*)salloc((size_t)8 * 32 * 12 * 4);
    float* WlT   = (float*)salloc((size_t)8 * 32 * 12 * 4);
    float* UlT   = (float*)salloc((size_t)8 * 32 * 12 * 4);
    int* nzf     = (int*)salloc((size_t)n_links * 4);
    int* counts  = (int*)salloc((size_t)n_links * 4);
    int* offsets = (int*)salloc((size_t)(n_links + 1) * 4);
    int* cursor  = (int*)salloc((size_t)n_links * 4);
    int* entries = (int*)salloc((size_t)n_ent * 4);
    (void)ws_size; (void)n_in; (void)out_size;

    int gmax = ( (n_paths > n_links ? n_paths : n_links) + 255 ) / 256;
    zero_counts_kernel<<<(n_links + 255)/256, 256, 0, stream>>>(counts, n_links);
    init_kernel<<<gmax, 256, 0, stream>>>(traffic, packets, eqlam, avgpkt,
                                          capacity, queues, path_state, link_state,
                                          n_paths, n_links);
    transpose_w4_kernel<<<(4*8*32*12 + 255)/256, 256, 0, stream>>>(
        Up, UpT, Wp, WpT, Wl, WlT, Ul, UlT);
    hist_kernel<<<(n_ent + 255)/256, 256, 0, stream>>>(link_to_path, counts, n_ent);
    scan_kernel<<<1, 1024, 0, stream>>>(counts, offsets, cursor, n_links);
    fill_kernel<<<(n_ent + 255)/256, 256, 0, stream>>>(link_to_path, cursor, entries, n_ent);

    int lgrid = (n_links + 63) / 64;
    // initial gates from init link_state
    gate_pre_kernel<<<lgrid, 256, 0, stream>>>(
        link_state, WpT, bip, bhp, Gi, nzf, n_links);
    for (int it = 0; it < T_ITERS; ++it) {
        path_kernel<<<(n_paths + 63)/64, 256, 0, stream>>>(
            Gi, nzf, path_state, link_to_path, UpT, bhp, n_paths);
        seg_sum_kernel<<<(n_links + 3)/4, 256, 0, stream>>>(
            path_state, offsets, entries, path_sum, n_links);
        link_gate_kernel<<<lgrid, 1024, 0, stream>>>(
            path_sum, link_state, WlT, UlT, bil, bhl,
            WpT, bip, bhp, Gi, nzf, n_links, (it < T_ITERS-1) ? 1 : 0);
    }
    readout_kernel<<<lgrid, 512, 0, stream>>>(
        link_state, W1, b1, W2, b2, W3, b3, (float*)d_out, n_links);
}

// Round 13
// 1234.272 us; speedup vs baseline: 1.0288x; 1.0288x over previous
//
#include <hip/hip_runtime.h>

#define DPDIM 32         // path/link state dim
#define GCOLS 96         // 3*DPDIM gate columns
#define PLEN 8
#define T_ITERS 8
#define RUNITS 256

// ---------------- fast activations (v_exp_f32 + v_rcp_f32) ----------------
__device__ __forceinline__ float fast_sigmoid(float a) {
    return __builtin_amdgcn_rcpf(1.0f + __expf(-a));
}
__device__ __forceinline__ float fast_tanh(float a) {
    // tanh(x) = 1 - 2/(1+e^{2x}); stable at both infinities
    return 1.0f - 2.0f * __builtin_amdgcn_rcpf(1.0f + __expf(2.0f * a));
}

#define ACC4F(A, s, V) \
    A.x = fmaf((s), (V).x, A.x); A.y = fmaf((s), (V).y, A.y); \
    A.z = fmaf((s), (V).z, A.z); A.w = fmaf((s), (V).w, A.w);

// ---------------- init states ----------------
__global__ __launch_bounds__(256) void init_kernel(
    const float* __restrict__ traffic, const float* __restrict__ packets,
    const float* __restrict__ eqlam, const float* __restrict__ avgpkt,
    const float* __restrict__ capacity, const float* __restrict__ queues,
    float* __restrict__ path_state, float* __restrict__ link_state,
    int n_paths, int n_links)
{
    int i = blockIdx.x * 256 + threadIdx.x;
    if (i < n_paths) {
        float4* row = (float4*)(path_state + (size_t)i * DPDIM);
        row[0] = make_float4(traffic[i], packets[i], eqlam[i], avgpkt[i]);
        float4 z = make_float4(0.f, 0.f, 0.f, 0.f);
        #pragma unroll
        for (int k = 1; k < 8; ++k) row[k] = z;
    }
    if (i < n_links) {
        float4* row = (float4*)(link_state + (size_t)i * DPDIM);
        row[0] = make_float4(capacity[i], queues[i], 0.f, 0.f);
        float4 z = make_float4(0.f, 0.f, 0.f, 0.f);
        #pragma unroll
        for (int k = 1; k < 8; ++k) row[k] = z;
    }
}

// ---------------- weight transpose: W[k][96] -> T[jb][k][12], 4 at once ----
__global__ __launch_bounds__(256) void transpose_w4_kernel(
    const float* __restrict__ W0, float* __restrict__ T0,
    const float* __restrict__ W1, float* __restrict__ T1,
    const float* __restrict__ W2, float* __restrict__ T2,
    const float* __restrict__ W3, float* __restrict__ T3)
{
    int i = blockIdx.x * 256 + threadIdx.x;
    if (i >= 4*8*32*12) return;
    int sel = i / (8*32*12);
    int j   = i % (8*32*12);
    int idx = j % 12;
    int k   = (j / 12) % 32;
    int jb  = j / (12*32);
    int gate = idx >> 2, c = idx & 3;
    const float* W = (sel == 0) ? W0 : (sel == 1) ? W1 : (sel == 2) ? W2 : W3;
    float*       T = (sel == 0) ? T0 : (sel == 1) ? T1 : (sel == 2) ? T2 : T3;
    T[j] = W[k*GCOLS + gate*32 + jb*4 + c];
}

// ---------------- CSR build ----------------
__global__ __launch_bounds__(256) void zero_counts_kernel(int* __restrict__ counts, int n) {
    int i = blockIdx.x * 256 + threadIdx.x;
    if (i < n) counts[i] = 0;
}
__global__ __launch_bounds__(256) void hist_kernel(
    const int* __restrict__ link_to_path, int* __restrict__ counts, int n) {
    int i = blockIdx.x * 256 + threadIdx.x;
    if (i < n) atomicAdd(&counts[link_to_path[i]], 1);
}
__global__ __launch_bounds__(1024) void scan_kernel(
    const int* __restrict__ counts, int* __restrict__ offsets,
    int* __restrict__ cursor, int n)
{
    __shared__ int s[1024];
    int t = threadIdx.x;
    int chunk = (n + 1023) >> 10;
    int lo = t * chunk;
    int hi = lo + chunk; if (hi > n) hi = n;
    int local = 0;
    for (int i = lo; i < hi; ++i) local += counts[i];
    s[t] = local;
    __syncthreads();
    for (int d = 1; d < 1024; d <<= 1) {
        int v = (t >= d) ? s[t - d] : 0;
        __syncthreads();
        s[t] += v;
        __syncthreads();
    }
    int base = (t > 0) ? s[t - 1] : 0;
    for (int i = lo; i < hi; ++i) {
        offsets[i] = base; cursor[i] = base; base += counts[i];
    }
    if (t == 1023) offsets[n] = s[1023];
}
__global__ __launch_bounds__(256) void fill_kernel(
    const int* __restrict__ link_to_path, int* __restrict__ cursor,
    int* __restrict__ entries, int n) {
    int e = blockIdx.x * 256 + threadIdx.x;
    if (e < n) {
        int l = link_to_path[e];
        int pos = atomicAdd(&cursor[l], 1);
        entries[pos] = e >> 3;   // path id (PLEN == 8)
    }
}

// ---------------- standalone gate_pre (pre-loop only) ----------------------
__global__ __launch_bounds__(256, 1) void gate_pre_kernel(
    const float* __restrict__ link_state,
    const float* __restrict__ WpT, const float* __restrict__ bip,
    const float* __restrict__ bhp,
    float* __restrict__ Gi, int* __restrict__ nzf, int n_links)
{
    int t = threadIdx.x;
    int pe = t & 63;
    int eps = __builtin_amdgcn_readfirstlane(t >> 6);
    int l = blockIdx.x * 64 + pe;
    bool act = l < n_links;
    int ll = act ? l : (n_links - 1);

    float x[DPDIM];
    bool nz = false;
    {
        const float4* row = (const float4*)(link_state + (size_t)ll * DPDIM);
        #pragma unroll
        for (int k4 = 0; k4 < 8; ++k4) {
            float4 v = row[k4];
            x[4*k4+0]=v.x; x[4*k4+1]=v.y; x[4*k4+2]=v.z; x[4*k4+3]=v.w;
            nz = nz || (v.x != 0.f) || (v.y != 0.f) || (v.z != 0.f) || (v.w != 0.f);
        }
    }
    float* G = Gi + (size_t)ll * GCOLS;
    int jb0 = eps*2;
    #pragma unroll 1
    for (int jj = 0; jj < 2; ++jj) {
        int jb = jb0 + jj;                              // wave-uniform
        float4 az = {0,0,0,0}, ar = {0,0,0,0}, ah = {0,0,0,0};
        const float* w = WpT + jb*(32*12);              // uniform s_load base
        #pragma unroll 4
        for (int k = 0; k < DPDIM; ++k) {
            float xk = x[k];
            const float4 wz = *(const float4*)(w);
            const float4 wr = *(const float4*)(w + 4);
            const float4 wh = *(const float4*)(w + 8);
            ACC4F(az, xk, wz); ACC4F(ar, xk, wr); ACC4F(ah, xk, wh);
            w += 12;
        }
        const float4 bz = *(const float4*)(bip + jb*4);
        const float4 br = *(const float4*)(bip + 32 + jb*4);
        const float4 bh = *(const float4*)(bip + 64 + jb*4);
        const float4 cz = *(const float4*)(bhp + jb*4);
        const float4 cr = *(const float4*)(bhp + 32 + jb*4);
        if (act) {
            *(float4*)(G + jb*4)      = make_float4(az.x+bz.x+cz.x, az.y+bz.y+cz.y,
                                                    az.z+bz.z+cz.z, az.w+bz.w+cz.w);
            *(float4*)(G + 32 + jb*4) = make_float4(ar.x+br.x+cr.x, ar.y+br.y+cr.y,
                                                    ar.z+br.z+cr.z, ar.w+br.w+cr.w);
            *(float4*)(G + 64 + jb*4) = make_float4(ah.x+bh.x, ah.y+bh.y,
                                                    ah.z+bh.z, ah.w+bh.w);
        }
    }
    if (act && eps == 0) nzf[l] = nz ? 1 : 0;
}

// ---------------- path GRU: 4 waves, Gi prefetch, own-h in registers -------
// Round-9/11 version (best measured ~96us). FROZEN.
__global__ __launch_bounds__(256, 1) void path_kernel(
    const float* __restrict__ Gi, const int* __restrict__ nzf,
    float* __restrict__ path_state, const int* __restrict__ link_to_path,
    const float* __restrict__ UpT, const float* __restrict__ bhp, int n_paths)
{
    __shared__ float hbuf[2*DPDIM*64];    // 16 KB, [buf][col][pathlane]
    int t = threadIdx.x;
    int pe = t & 63;
    int eps = __builtin_amdgcn_readfirstlane(t >> 6);
    int p = blockIdx.x * 64 + pe;
    bool act = p < n_paths;
    int pp = act ? p : (n_paths - 1);

    float4 hownA, hownB;                  // own 8 columns, live in registers
    {
        const float4* row = (const float4*)(path_state + (size_t)pp * DPDIM + eps*8);
        hownA = row[0]; hownB = row[1];
        int c0 = eps*8;
        hbuf[(c0+0)*64 + pe] = hownA.x; hbuf[(c0+1)*64 + pe] = hownA.y;
        hbuf[(c0+2)*64 + pe] = hownA.z; hbuf[(c0+3)*64 + pe] = hownA.w;
        hbuf[(c0+4)*64 + pe] = hownB.x; hbuf[(c0+5)*64 + pe] = hownB.y;
        hbuf[(c0+6)*64 + pe] = hownB.z; hbuf[(c0+7)*64 + pe] = hownB.w;
    }

    const int jbA = eps*2, jbB = eps*2 + 1;
    const float4 ahA0 = *(const float4*)(bhp + 64 + jbA*4);   // uniform, hoisted
    const float4 ahB0 = *(const float4*)(bhp + 64 + jbB*4);
    const float* wA0 = UpT + jbA*(32*12);                     // uniform bases
    const float* wB0 = UpT + jbB*(32*12);

    // prefetch pipeline: l_s current link, l_n next link
    int l_s = link_to_path[pp*PLEN + 0];
    int l_n = link_to_path[pp*PLEN + 1];
    const float* G0 = Gi + (size_t)l_s * GCOLS;
    float4 pazA = *(const float4*)(G0 + jbA*4);
    float4 parA = *(const float4*)(G0 + 32 + jbA*4);
    float4 pgihA= *(const float4*)(G0 + 64 + jbA*4);
    float4 pazB = *(const float4*)(G0 + jbB*4);
    float4 parB = *(const float4*)(G0 + 32 + jbB*4);
    float4 pgihB= *(const float4*)(G0 + 64 + jbB*4);
    int pnz = nzf[l_s];

    __syncthreads();

    int cur = 0;
    #pragma unroll 1
    for (int s = 0; s < PLEN; ++s) {
        float4 azA = pazA, arA = parA, gihA = pgihA;
        float4 azB = pazB, arB = parB, gihB = pgihB;
        bool nz = act && (pnz != 0);
        if (s < PLEN-1) {                       // issue next-step gathers NOW
            const float* G1 = Gi + (size_t)l_n * GCOLS;
            pazA = *(const float4*)(G1 + jbA*4);
            parA = *(const float4*)(G1 + 32 + jbA*4);
            pgihA= *(const float4*)(G1 + 64 + jbA*4);
            pazB = *(const float4*)(G1 + jbB*4);
            parB = *(const float4*)(G1 + 32 + jbB*4);
            pgihB= *(const float4*)(G1 + 64 + jbB*4);
            pnz = nzf[l_n];
            if (s < PLEN-2) l_n = link_to_path[pp*PLEN + s + 2];
        }
        const float* hold = hbuf + cur*(DPDIM*64) + pe;
        float* hnew = hbuf + (cur^1)*(DPDIM*64) + pe;
#define PWC1(C, j, az, ar, gih, ah, jb, HOWN) { \
        float zz = fast_sigmoid((az).C); \
        float rr = fast_sigmoid((ar).C); \
        float cc = fast_tanh((gih).C + rr * (ah).C); \
        float ho = (HOWN).C; \
        float nx = nz ? (cc + zz * (ho - cc)) : ho; \
        hnew[((jb)*4+(j))*64] = nx; \
        (HOWN).C = nx; }
        {   // jb A
            float4 ah = ahA0;
            const float* w = wA0;
            #pragma unroll 4
            for (int k = 0; k < DPDIM; ++k) {
                float hk = hold[k*64];
                const float4 wz = *(const float4*)(w);
                const float4 wr = *(const float4*)(w + 4);
                const float4 wh = *(const float4*)(w + 8);
                ACC4F(azA, hk, wz); ACC4F(arA, hk, wr); ACC4F(ah, hk, wh);
                w += 12;
            }
            PWC1(x, 0, azA, arA, gihA, ah, jbA, hownA)
            PWC1(y, 1, azA, arA, gihA, ah, jbA, hownA)
            PWC1(z, 2, azA, arA, gihA, ah, jbA, hownA)
            PWC1(w, 3, azA, arA, gihA, ah, jbA, hownA)
        }
        {   // jb B
            float4 ah = ahB0;
            const float* w = wB0;
            #pragma unroll 4
            for (int k = 0; k < DPDIM; ++k) {
                float hk = hold[k*64];
                const float4 wz = *(const float4*)(w);
                const float4 wr = *(const float4*)(w + 4);
                const float4 wh = *(const float4*)(w + 8);
                ACC4F(azB, hk, wz); ACC4F(arB, hk, wr); ACC4F(ah, hk, wh);
                w += 12;
            }
            PWC1(x, 0, azB, arB, gihB, ah, jbB, hownB)
            PWC1(y, 1, azB, arB, gihB, ah, jbB, hownB)
            PWC1(z, 2, azB, arB, gihB, ah, jbB, hownB)
            PWC1(w, 3, azB, arB, gihB, ah, jbB, hownB)
        }
#undef PWC1
        __syncthreads();     // hnew complete + hold reads done across waves
        cur ^= 1;
    }

    if (act) {   // own columns already in registers
        *(float4*)(path_state + (size_t)p * DPDIM + eps*8)     = hownA;
        *(float4*)(path_state + (size_t)p * DPDIM + eps*8 + 4) = hownB;
    }
}

// ---------------- segment sum: 1 wave per link, 2-way split, 8-deep MLP ----
// Round-11 structure; accumulator depth 4 -> 8 (16-entry chunks per half) to
// double outstanding gathers per lane (avg 20 entries/half: 1 chunk + tail).
// Final reduce regroups as (pairs of pairs) - FP order change within the
// tolerance regime established in round 11.
__global__ __launch_bounds__(256) void seg_sum_kernel(
    const float* __restrict__ path_state, const int* __restrict__ offsets,
    const int* __restrict__ entries, float* __restrict__ path_sum, int n_links)
{
    int t = threadIdx.x;
    int lane = t & 63;
    int wid = t >> 6;               // wave 0..3 -> link
    int d = lane & 31;
    int half = lane >> 5;           // 0 or 1
    int l = blockIdx.x * 4 + wid;
    if (l >= n_links) return;
    int beg = offsets[l], end = offsets[l+1];
    float a0 = 0.f, a1 = 0.f, a2 = 0.f, a3 = 0.f;
    float a4 = 0.f, a5 = 0.f, a6 = 0.f, a7 = 0.f;
    int q = beg + half;
    for (; q + 14 < end; q += 16) {
        int p0 = entries[q],    p1 = entries[q+2];
        int p2 = entries[q+4],  p3 = entries[q+6];
        int p4 = entries[q+8],  p5 = entries[q+10];
        int p6 = entries[q+12], p7 = entries[q+14];
        a0 += path_state[(size_t)p0 * DPDIM + d];
        a1 += path_state[(size_t)p1 * DPDIM + d];
        a2 += path_state[(size_t)p2 * DPDIM + d];
        a3 += path_state[(size_t)p3 * DPDIM + d];
        a4 += path_state[(size_t)p4 * DPDIM + d];
        a5 += path_state[(size_t)p5 * DPDIM + d];
        a6 += path_state[(size_t)p6 * DPDIM + d];
        a7 += path_state[(size_t)p7 * DPDIM + d];
    }
    for (; q + 6 < end; q += 8) {
        int p0 = entries[q],   p1 = entries[q+2];
        int p2 = entries[q+4], p3 = entries[q+6];
        a0 += path_state[(size_t)p0 * DPDIM + d];
        a1 += path_state[(size_t)p1 * DPDIM + d];
        a2 += path_state[(size_t)p2 * DPDIM + d];
        a3 += path_state[(size_t)p3 * DPDIM + d];
    }
    for (; q < end; q += 2)
        a0 += path_state[(size_t)entries[q] * DPDIM + d];
    float s = ((a0 + a1) + (a2 + a3)) + ((a4 + a5) + (a6 + a7));
    s += __shfl_down(s, 32);        // combine the two halves (wave64)
    if (half == 0)
        path_sum[(size_t)l * DPDIM + d] = s;
}

// ---------------- fused: link GRU + next-iter gate_pre (8 waves) -----------
// Round-11 version (k-split of round 12 refuted: -17us). do_gate==0 on the
// final iteration (gate output never consumed).
__global__ __launch_bounds__(512, 1) void link_gate_kernel(
    const float* __restrict__ path_sum, float* __restrict__ link_state,
    const float* __restrict__ WlT, const float* __restrict__ UlT,
    const float* __restrict__ bil, const float* __restrict__ bhl,
    const float* __restrict__ WpT, const float* __restrict__ bip,
    const float* __restrict__ bhp,
    float* __restrict__ Gi, int* __restrict__ nzf, int n_links, int do_gate)
{
    __shared__ float xbuf[DPDIM*64];   // 8 KB [col][lane]  (path_sum)
    __shared__ float hbuf[DPDIM*64];   // 8 KB [col][lane]  (old h)
    __shared__ float nbuf[DPDIM*64];   // 8 KB [col][lane]  (new h)
    int t = threadIdx.x;
    int pe = t & 63;
    int eps = __builtin_amdgcn_readfirstlane(t >> 6);   // 0..7
    int l = blockIdx.x * 64 + pe;
    bool act = l < n_links;
    int ll = act ? l : (n_links - 1);
    const int jb = eps;
    int c0 = jb*4;
    {
        float4 x0 = *(const float4*)(path_sum   + (size_t)ll * DPDIM + c0);
        float4 h0 = *(const float4*)(link_state + (size_t)ll * DPDIM + c0);
        xbuf[(c0+0)*64 + pe] = x0.x; xbuf[(c0+1)*64 + pe] = x0.y;
        xbuf[(c0+2)*64 + pe] = x0.z; xbuf[(c0+3)*64 + pe] = x0.w;
        hbuf[(c0+0)*64 + pe] = h0.x; hbuf[(c0+1)*64 + pe] = h0.y;
        hbuf[(c0+2)*64 + pe] = h0.z; hbuf[(c0+3)*64 + pe] = h0.w;
    }
    __syncthreads();

    // ---- phase 1: link GRU (one jb per wave) ----
    {
        float4 az = {0,0,0,0}, ar = {0,0,0,0}, ai = {0,0,0,0}, ah = {0,0,0,0};
        const float* w = WlT + jb*(32*12);               // uniform s_load
        const float* u = UlT + jb*(32*12);               // uniform s_load
        #pragma unroll 4
        for (int k = 0; k < DPDIM; ++k) {
            float xk = xbuf[k*64 + pe];
            float hk = hbuf[k*64 + pe];
            const float4 wz = *(const float4*)(w);
            const float4 wr = *(const float4*)(w + 4);
            const float4 wh = *(const float4*)(w + 8);
            const float4 uz = *(const float4*)(u);
            const float4 ur = *(const float4*)(u + 4);
            const float4 uh = *(const float4*)(u + 8);
            ACC4F(az, xk, wz); ACC4F(az, hk, uz);
            ACC4F(ar, xk, wr); ACC4F(ar, hk, ur);
            ACC4F(ai, xk, wh);
            ACC4F(ah, hk, uh);
            w += 12; u += 12;
        }
        const float4 BZI = *(const float4*)(bil + jb*4);
        const float4 BRI = *(const float4*)(bil + 32 + jb*4);
        const float4 BHI = *(const float4*)(bil + 64 + jb*4);
        const float4 BZH = *(const float4*)(bhl + jb*4);
        const float4 BRH = *(const float4*)(bhl + 32 + jb*4);
        const float4 BHH = *(const float4*)(bhl + 64 + jb*4);
        float4 hv;
#define LWC(C, j, DST) { \
        float z = fast_sigmoid(az.C + BZI.C + BZH.C); \
        float r = fast_sigmoid(ar.C + BRI.C + BRH.C); \
        float c = fast_tanh(ai.C + BHI.C + r * (ah.C + BHH.C)); \
        float ho = hbuf[(jb*4+j)*64 + pe]; \
        DST = z*ho + (1.f - z)*c; }
        LWC(x, 0, hv.x) LWC(y, 1, hv.y) LWC(z, 2, hv.z) LWC(w, 3, hv.w)
#undef LWC
        nbuf[(c0+0)*64 + pe] = hv.x; nbuf[(c0+1)*64 + pe] = hv.y;
        nbuf[(c0+2)*64 + pe] = hv.z; nbuf[(c0+3)*64 + pe] = hv.w;
        if (act) *(float4*)(link_state + (size_t)ll * DPDIM + c0) = hv;
    }
    if (!do_gate) return;
    __syncthreads();

    // ---- phase 2: gate_pre for the NEXT iteration, x = new h (nbuf) ----
    {
        float* G = Gi + (size_t)ll * GCOLS;
        float4 az = {0,0,0,0}, ar = {0,0,0,0}, ah = {0,0,0,0};
        const float* w = WpT + jb*(32*12);               // uniform s_load
        #pragma unroll 4
        for (int k = 0; k < DPDIM; ++k) {
            float xk = nbuf[k*64 + pe];
            const float4 wz = *(const float4*)(w);
            const float4 wr = *(const float4*)(w + 4);
            const float4 wh = *(const float4*)(w + 8);
            ACC4F(az, xk, wz); ACC4F(ar, xk, wr); ACC4F(ah, xk, wh);
            w += 12;
        }
        const float4 bz = *(const float4*)(bip + jb*4);
        const float4 br = *(const float4*)(bip + 32 + jb*4);
        const float4 bh = *(const float4*)(bip + 64 + jb*4);
        const float4 cz = *(const float4*)(bhp + jb*4);
        const float4 cr = *(const float4*)(bhp + 32 + jb*4);
        if (act) {
            *(float4*)(G + jb*4)      = make_float4(az.x+bz.x+cz.x, az.y+bz.y+cz.y,
                                                    az.z+bz.z+cz.z, az.w+bz.w+cz.w);
            *(float4*)(G + 32 + jb*4) = make_float4(ar.x+br.x+cr.x, ar.y+br.y+cr.y,
                                                    ar.z+br.z+cr.z, ar.w+br.w+cr.w);
            *(float4*)(G + 64 + jb*4) = make_float4(ah.x+bh.x, ah.y+bh.y,
                                                    ah.z+bh.z, ah.w+bh.w);
        }
        if (eps == 0) {
            bool nz = false;
            #pragma unroll 4
            for (int k = 0; k < DPDIM; ++k)
                nz = nz || (nbuf[k*64 + pe] != 0.f);
            if (act) nzf[l] = nz ? 1 : 0;
        }
    }
}

// ---------------- readout: lane=link, scalar weights -----------------------
__global__ __launch_bounds__(512, 1) void readout_kernel(
    const float* __restrict__ link_state,
    const float* __restrict__ W1, const float* __restrict__ b1,
    const float* __restrict__ W2, const float* __restrict__ b2,
    const float* __restrict__ W3, const float* __restrict__ b3,
    float* __restrict__ out, int n_links)
{
    __shared__ float s_m[64*257];     // 64.25 KB, r1[link][col] (pad 257)
    __shared__ float s_part[8*64];
    int t = threadIdx.x;
    int u = t & 63;                                     // link lane
    int g = __builtin_amdgcn_readfirstlane(t >> 6);     // wave id 0..7
    int l = blockIdx.x * 64 + u;
    bool act = l < n_links;
    int ll = act ? l : (n_links - 1);

    float x[DPDIM];
    {
        const float4* row = (const float4*)(link_state + (size_t)ll * DPDIM);
        #pragma unroll
        for (int k4 = 0; k4 < 8; ++k4) {
            float4 v = row[k4];
            x[4*k4+0]=v.x; x[4*k4+1]=v.y; x[4*k4+2]=v.z; x[4*k4+3]=v.w;
        }
    }
    // r1 for cols [32g, 32g+32)
    {
        const float* w1p = W1 + 32*g;                   // uniform base
        const float* b1p = b1 + 32*g;
        float acc1[32];
        #pragma unroll
        for (int c = 0; c < 32; ++c) acc1[c] = b1p[c];
        #pragma unroll 2
        for (int k = 0; k < DPDIM; ++k) {
            float xk = x[k];
            #pragma unroll
            for (int c = 0; c < 32; ++c)
                acc1[c] = fmaf(xk, w1p[k*RUNITS + c], acc1[c]);
        }
        #pragma unroll
        for (int c = 0; c < 32; ++c)
            s_m[u*257 + 32*g + c] = fmaxf(acc1[c], 0.f);
    }
    __syncthreads();
    // r2 for cols [32g,32g+32) of link u: 1 LDS read per k -> 32 FMA
    float acc[32];
    {
        const float* w2p = W2 + 32*g;                   // uniform base
        const float* b2p = b2 + 32*g;
        #pragma unroll
        for (int c = 0; c < 32; ++c) acc[c] = b2p[c];
        const float* rrow = s_m + u*257;
        #pragma unroll 2
        for (int k = 0; k < RUNITS; ++k) {
            float rk = rrow[k];
            #pragma unroll
            for (int c = 0; c < 32; ++c)
                acc[c] = fmaf(rk, w2p[k*RUNITS + c], acc[c]);
        }
    }
    // partial dot with w3
    {
        const float* w3p = W3 + 32*g;
        float psum = 0.f;
        #pragma unroll
        for (int c = 0; c < 32; ++c)
            psum += fmaxf(acc[c], 0.f) * w3p[c];
        s_part[g*64 + u] = psum;
    }
    __syncthreads();
    if (t < 64 && act) {
        float ssum = b3[0];
        #pragma unroll
        for (int gg = 0; gg < 8; ++gg) ssum += s_part[gg*64 + u];
        out[l] = ssum;
    }
}

// ---------------- launch ----------------
extern "C" void kernel_launch(void* const* d_in, const int* in_sizes, int n_in,
                              void* d_out, int out_size, void* d_ws, size_t ws_size,
                              hipStream_t stream)
{
    const float* traffic  = (const float*)d_in[0];
    const float* packets  = (const float*)d_in[1];
    const float* eqlam    = (const float*)d_in[2];
    const float* avgpkt   = (const float*)d_in[3];
    const float* capacity = (const float*)d_in[4];
    const float* queues   = (const float*)d_in[5];
    const int* link_to_path = (const int*)d_in[6];
    const float* Wp  = (const float*)d_in[13];
    const float* Up  = (const float*)d_in[14];
    const float* bip = (const float*)d_in[15];
    const float* bhp = (const float*)d_in[16];
    const float* Wl  = (const float*)d_in[17];
    const float* Ul  = (const float*)d_in[18];
    const float* bil = (const float*)d_in[19];
    const float* bhl = (const float*)d_in[20];
    const float* W1  = (const float*)d_in[21];
    const float* b1  = (const float*)d_in[22];
    const float* W2  = (const float*)d_in[23];
    const float* b2  = (const float*)d_in[24];
    const float* W3  = (const float*)d_in[25];
    const float* b3  = (const float*)d_in[26];
    const int n_paths = in_sizes[0];     // 100000
    const int n_links = in_sizes[4];     // 20000
    const int n_ent   = in_sizes[6];     // 800000

    char* ws = (char*)d_ws;
    size_t off = 0;
    auto salloc = [&](size_t bytes) -> void* {
        void* p = ws + off;
        off += (bytes + 255) & ~size_t(255);
        return p;
    };
    float* path_state = (float*)salloc((size_t)n_paths * DPDIM * 4);
    float* link_state = (float*)salloc((size_t)n_links * DPDIM * 4);
    float* Gi         = (float*)salloc((size_t)n_links * GCOLS * 4);
    float* path_sum   = (float*)salloc((size_t)n_links * DPDIM * 4);
    float* UpT   = (float*)salloc((size_t)8 * 32 * 12 * 4);
    float* WpT   = (float*)salloc((size_t)8 * 32 * 12 * 4);
    float* WlT   = (float*)salloc((size_t)8 * 32 * 12 * 4);
    float* UlT   = (float*)salloc((size_t)8 * 32 * 12 * 4);
    int* nzf     = (int*)salloc((size_t)n_links * 4);
    int* counts  = (int*)salloc((size_t)n_links * 4);
    int* offsets = (int*)salloc((size_t)(n_links + 1) * 4);
    int* cursor  = (int*)salloc((size_t)n_links * 4);
    int* entries = (int*)salloc((size_t)n_ent * 4);
    (void)ws_size; (void)n_in; (void)out_size;

    int gmax = ( (n_paths > n_links ? n_paths : n_links) + 255 ) / 256;
    zero_counts_kernel<<<(n_links + 255)/256, 256, 0, stream>>>(counts, n_links);
    init_kernel<<<gmax, 256, 0, stream>>>(traffic, packets, eqlam, avgpkt,
                                          capacity, queues, path_state, link_state,
                                          n_paths, n_links);
    transpose_w4_kernel<<<(4*8*32*12 + 255)/256, 256, 0, stream>>>(
        Up, UpT, Wp, WpT, Wl, WlT, Ul, UlT);
    hist_kernel<<<(n_ent + 255)/256, 256, 0, stream>>>(link_to_path, counts, n_ent);
    scan_kernel<<<1, 1024, 0, stream>>>(counts, offsets, cursor, n_links);
    fill_kernel<<<(n_ent + 255)/256, 256, 0, stream>>>(link_to_path, cursor, entries, n_ent);

    int lgrid = (n_links + 63) / 64;
    // initial gates from init link_state
    gate_pre_kernel<<<lgrid, 256, 0, stream>>>(
        link_state, WpT, bip, bhp, Gi, nzf, n_links);
    for (int it = 0; it < T_ITERS; ++it) {
        path_kernel<<<(n_paths + 63)/64, 256, 0, stream>>>(
            Gi, nzf, path_state, link_to_path, UpT, bhp, n_paths);
        seg_sum_kernel<<<(n_links + 3)/4, 256, 0, stream>>>(
            path_state, offsets, entries, path_sum, n_links);
        link_gate_kernel<<<lgrid, 512, 0, stream>>>(
            path_sum, link_state, WlT, UlT, bil, bhl,
            WpT, bip, bhp, Gi, nzf, n_links, (it < T_ITERS-1) ? 1 : 0);
    }
    readout_kernel<<<lgrid, 512, 0, stream>>>(
        link_state, W1, b1, W2, b2, W3, b3, (float*)d_out, n_links);
}